// Round 24
// baseline (179.627 us; speedup 1.0000x reference)
//
#include <hip/hip_runtime.h>
#include <math.h>

#define DIN 256
#define HDIM 128
#define NCRIT 10
#define BSH 9
#define EPB 4096

typedef __bf16 bf16;
typedef bf16 bf16x8 __attribute__((ext_vector_type(8)));
typedef float f32x4 __attribute__((ext_vector_type(4)));
typedef float f32x2 __attribute__((ext_vector_type(2)));

static inline size_t alignup(size_t x, size_t a) { return (x + a - 1) & ~(a - 1); }

__device__ inline float bflo(unsigned v) { return __uint_as_float(v << 16); }
__device__ inline float bfhi(unsigned v) { return __uint_as_float(v & 0xffff0000u); }

__device__ inline bf16x8 cvt8(float4 v0, float4 v1) {
    bf16x8 w;
    w[0] = (bf16)v0.x; w[1] = (bf16)v0.y; w[2] = (bf16)v0.z; w[3] = (bf16)v0.w;
    w[4] = (bf16)v1.x; w[5] = (bf16)v1.y; w[6] = (bf16)v1.z; w[7] = (bf16)v1.w;
    return w;
}

__device__ inline void gl_lds16(const void* g, void* l) {
    __builtin_amdgcn_global_load_lds(
        (const __attribute__((address_space(1))) unsigned*)g,
        (__attribute__((address_space(3))) unsigned*)l, 16, 0, 0);
}

// ---------- k1: wconv(0..63) + Wcomb(64..79) + cq(80) || block-staged bucket append ----------
// bpool entries packed: (src << 9) | (dst & 511)
__global__ __launch_bounds__(256) void k_bucket2(
    const int* __restrict__ src, const int* __restrict__ dst, int E,
    int* __restrict__ bcnt, int* __restrict__ bpool, int capb, int nB,
    const float* __restrict__ Wl, const float* __restrict__ Wr,
    const float* __restrict__ Wres,
    const float* __restrict__ wscore, const float* __restrict__ wcrit,
    const float* __restrict__ bres, const float* __restrict__ bscore,
    const float* __restrict__ bcrit,
    bf16* __restrict__ WcatT, float* __restrict__ cq)
{
    int t = threadIdx.x;
    int b = blockIdx.x;
    if (b < 64) {
        int base = (b * 256 + t) * 4;
        int r = base >> 8;
        int c0 = base & 255;
        const float* W = (r < 128) ? Wl : Wr;
        float4 v = *(const float4*)&W[(size_t)(r & 127) * 256 + c0];
        bf16 o[4] = {(bf16)v.x, (bf16)v.y, (bf16)v.z, (bf16)v.w};
        char* d = (char*)WcatT + ((((size_t)(c0 >> 3) * 272 + r) << 4) + ((c0 & 7) << 1));
        *(uint2*)d = *(const uint2*)o;
        return;
    } else if (b < 80) {
        int q = b - 64;
        int k = t;
        float s = 0.f;
        if (q < 11) {
            const float* wepi = (q == 0) ? wscore : &wcrit[(size_t)(q - 1) * HDIM];
            for (int c = 0; c < HDIM; ++c)
                s += wepi[c] * Wres[(size_t)c * 256 + k];
        }
        char* d = (char*)WcatT + ((((size_t)(k >> 3) * 272 + 256 + q) << 4) + ((k & 7) << 1));
        *(bf16*)d = (bf16)s;
        return;
    } else if (b == 80) {
        if (t < 11) {
            const float* wepi = (t == 0) ? wscore : &wcrit[(size_t)(t - 1) * HDIM];
            float s = 0.f;
            for (int c = 0; c < HDIM; ++c) s += bres[c] * wepi[c];
            cq[t] = s + ((t == 0) ? bscore[0] : bcrit[t - 1]);
        }
        return;
    }

    __shared__ int lcnt[256], lbase[256], lcur[256], gbase[256];
    __shared__ int stage[EPB];

    int blk = b - 81;
    int base = blk * EPB;
    int m = min(EPB, E - base);
    if (m <= 0) return;

    lcnt[t] = 0;
    __syncthreads();
    for (int i = t; i < m; i += 256)
        atomicAdd(&lcnt[dst[base + i] >> BSH], 1);
    __syncthreads();
    int c0 = lcnt[t];
    for (int d = 1; d < 256; d <<= 1) {
        int a0 = lcnt[t];
        int b0 = (t >= d) ? lcnt[t - d] : 0;
        __syncthreads();
        lcnt[t] = a0 + b0;
        __syncthreads();
    }
    int e0 = lcnt[t] - c0;
    lbase[t] = e0;
    lcur[t] = e0;
    if (t < nB && c0 > 0) gbase[t] = atomicAdd(&bcnt[t * 16], c0);
    __syncthreads();
    for (int i = t; i < m; i += 256) {
        int s2 = src[base + i], d = dst[base + i];
        int bk = d >> BSH;
        int pos = atomicAdd(&lcur[bk], 1);
        stage[pos] = (s2 << BSH) | (d & 511);
    }
    __syncthreads();
    int wv = t >> 6, lane = t & 63;
    for (int bk = wv; bk < nB; bk += 4) {
        int lb = lbase[bk];
        int cb = lcnt[bk] - lb;
        if (cb == 0) continue;
        int gb = gbase[bk];
        int* dstp = bpool + (size_t)bk * capb + gb;
        for (int j = lane; j < cb && gb + j < capb; j += 64)
            dstp[j] = stage[lb + j];
    }
}

// ---------- k2: per-bucket finalize (lists padded to x16; pads -> zero-row index n) ----------
__global__ __launch_bounds__(256) void k_fin(const int* __restrict__ bcnt,
                                             const int* __restrict__ bpool, int capb,
                                             int n, int2* __restrict__ ocnt,
                                             int* __restrict__ sidx,
                                             unsigned char* __restrict__ yq) {
    __shared__ int lcnt[512], lcur[512];
    int b = blockIdx.x, t = threadIdx.x;
    int m = min(bcnt[b * 16], capb);
    const int* ep = bpool + (size_t)b * capb;

    if (b == 0 && t < 8)
        *(uint4*)(yq + (size_t)n * 128 + t * 16) = make_uint4(0, 0, 0, 0);

    lcnt[t] = 0; lcnt[t + 256] = 0;
    __syncthreads();
    for (int i = t; i < m; i += 256)
        atomicAdd(&lcnt[ep[i] & 511], 1);
    __syncthreads();
    int c0 = lcnt[t], c1 = lcnt[t + 256];
    int p0 = (c0 + 15) & ~15, p1 = (c1 + 15) & ~15;   // pad to x16
    __syncthreads();
    lcnt[t] = p0; lcnt[t + 256] = p1;
    __syncthreads();
    for (int d = 1; d < 512; d <<= 1) {
        int a0 = lcnt[t], a1 = lcnt[t + 256];
        int b0 = (t >= d) ? lcnt[t - d] : 0;
        int b1 = ((t + 256) >= d) ? lcnt[t + 256 - d] : 0;
        __syncthreads();
        lcnt[t] = a0 + b0; lcnt[t + 256] = a1 + b1;
        __syncthreads();
    }
    int e0 = lcnt[t] - p0, e1 = lcnt[t + 256] - p1;
    int nbase = b << BSH;
    int sbase = b * capb;
    lcur[t] = e0; lcur[t + 256] = e1;
    int n0 = nbase + t, n1 = nbase + t + 256;
    if (n0 < n) ocnt[n0] = make_int2(sbase + e0, c0);
    if (n1 < n) ocnt[n1] = make_int2(sbase + e1, c1);
    for (int j = c0; j < p0; j++) sidx[sbase + e0 + j] = n;
    for (int j = c1; j < p1; j++) sidx[sbase + e1 + j] = n;
    __syncthreads();
    for (int i = t; i < m; i += 256) {
        int e = ep[i];
        int pos = atomicAdd(&lcur[e & 511], 1);
        sidx[sbase + pos] = (int)(((unsigned)e) >> BSH);
    }
}

// ---------- k3: barrier-free GEMM (z' = zr + bl folded) ----------
__global__ __launch_bounds__(512) void k_gemm(
    const float* __restrict__ x, const bf16* __restrict__ WcatT, int n,
    unsigned char* __restrict__ yq, bf16* __restrict__ z, float* __restrict__ w,
    const float* __restrict__ bl)
{
    __shared__ __align__(16) char smem[147456];
    int t = threadIdx.x;
    int wv = t >> 6, lane = t & 63;
    int l15 = lane & 15, kq = lane >> 4;

    {
        int cbase0 = wv * 64;
        #pragma unroll
        for (int i = 0; i < 17; i++) {
            int cbase = i * 512 + cbase0;
            gl_lds16((const char*)WcatT + (((size_t)cbase + lane) << 4),
                     smem + ((size_t)cbase << 4));
        }
    }
    __syncthreads();

    char* scr = smem + 139264 + wv * 1024;
    int rrow = lane >> 2, rc4 = (lane & 3) * 4;

    int nTiles = (n + 127) >> 7;
    for (int tile = blockIdx.x; tile < nTiles; tile += gridDim.x) {
        int rowb = tile * 128 + wv * 16;
        int myrow = rowb + l15;
        const float* ap = x + (size_t)(myrow < n ? myrow : (n - 1)) * 256 + kq * 8;

        float4 xa[8], xb[8];
        #pragma unroll
        for (int s = 0; s < 8; s++) {
            xa[s] = *(const float4*)(ap + s * 32);
            xb[s] = *(const float4*)(ap + s * 32 + 4);
        }

        f32x4 acc[17];
        #pragma unroll
        for (int C = 0; C < 17; C++) acc[C] = (f32x4){0.f, 0.f, 0.f, 0.f};

        #pragma unroll
        for (int s = 0; s < 8; s++) {
            bf16x8 afr = cvt8(xa[s], xb[s]);
            int sbase = ((s * 4 + kq) * 272 + l15) << 4;
            #pragma unroll
            for (int C = 0; C < 17; C++) {
                bf16x8 b = *(const bf16x8*)(smem + sbase + C * 256);
                acc[C] = __builtin_amdgcn_mfma_f32_16x16x32_bf16(afr, b, acc[C], 0, 0, 0);
            }
        }

        int gr = rowb + rrow;
        bool ok = gr < n;
        #pragma unroll
        for (int C = 0; C < 17; C++) {
            #pragma unroll
            for (int j = 0; j < 4; j++)
                *(float*)(scr + ((((kq << 2) + j) * 16 + l15) << 2)) = acc[C][j];
            f32x4 vv = *(const f32x4*)(scr + ((rrow * 16 + rc4) << 2));
            if (C < 8) {
                unsigned pk = (unsigned)__builtin_amdgcn_cvt_pk_fp8_f32(vv[0], vv[1], 0, false);
                pk = (unsigned)__builtin_amdgcn_cvt_pk_fp8_f32(vv[2], vv[3], pk, true);
                if (ok) *(unsigned*)(yq + (size_t)gr * 128 + C * 16 + rc4) = pk;
            } else if (C < 16) {
                float4 blv = *(const float4*)&bl[(C - 8) * 16 + rc4];
                bf16 o[4] = {(bf16)(vv[0] + blv.x), (bf16)(vv[1] + blv.y),
                             (bf16)(vv[2] + blv.z), (bf16)(vv[3] + blv.w)};
                if (ok) *(uint2*)((char*)z + (size_t)gr * 256 + (C - 8) * 32 + rc4 * 2) =
                            *(const uint2*)o;
            } else {
                if (ok) *(f32x4*)(w + (size_t)gr * 16 + rc4) = vv;
            }
        }
    }
}

// ---------- k4: gather, 8B/lane, single branch-free x16-padded loop ----------
__global__ __launch_bounds__(256) void k_gather(
    const unsigned char* __restrict__ yq, const bf16* __restrict__ z,
    const float* __restrict__ w, const float* __restrict__ cq,
    const int2* __restrict__ ocnt, const int* __restrict__ sidx,
    const float* __restrict__ wscore, const float* __restrict__ wcrit,
    const float* __restrict__ rrs, const float* __restrict__ palpha,
    int n, float* __restrict__ outF, float* __restrict__ outL)
{
    __shared__ bf16 wsb[11 * 128];
    int t = threadIdx.x;
    for (int i = t; i < 11 * 128; i += 256) {
        int q = i >> 7, c = i & 127;
        wsb[i] = (bf16)((q == 0) ? wscore[c] : wcrit[(size_t)(q - 1) * HDIM + c]);
    }
    __syncthreads();

    int node = blockIdx.x * 4 + (t >> 6);
    if (node >= n) return;
    int lane = t & 63, g4 = lane >> 4, c16 = lane & 15;

    int2 oc = ocnt[node];                 // one dependent load: {beg, len}
    uint4 zv = *(const uint4*)((const char*)z + (size_t)node * 256 + c16 * 16);

    const unsigned char* ybase = yq + c16 * 8;
    int beg = oc.x, len = oc.y;
    int lenp = (len + 15) & ~15;
    const int* sp = sidx + beg;

    f32x2 a01 = {0.f, 0.f}, a23 = {0.f, 0.f}, a45 = {0.f, 0.f}, a67 = {0.f, 0.f};
    for (int e = 0; e < lenp; e += 16) {
        int4 iv = *(const int4*)&sp[e + g4 * 4];
        uint2 v0 = *(const uint2*)(ybase + ((size_t)(unsigned)iv.x << 7));
        uint2 v1 = *(const uint2*)(ybase + ((size_t)(unsigned)iv.y << 7));
        uint2 v2 = *(const uint2*)(ybase + ((size_t)(unsigned)iv.z << 7));
        uint2 v3 = *(const uint2*)(ybase + ((size_t)(unsigned)iv.w << 7));
        a01 += __builtin_amdgcn_cvt_pk_f32_fp8(v0.x, false)
             + __builtin_amdgcn_cvt_pk_f32_fp8(v1.x, false)
             + __builtin_amdgcn_cvt_pk_f32_fp8(v2.x, false)
             + __builtin_amdgcn_cvt_pk_f32_fp8(v3.x, false);
        a23 += __builtin_amdgcn_cvt_pk_f32_fp8(v0.x, true)
             + __builtin_amdgcn_cvt_pk_f32_fp8(v1.x, true)
             + __builtin_amdgcn_cvt_pk_f32_fp8(v2.x, true)
             + __builtin_amdgcn_cvt_pk_f32_fp8(v3.x, true);
        a45 += __builtin_amdgcn_cvt_pk_f32_fp8(v0.y, false)
             + __builtin_amdgcn_cvt_pk_f32_fp8(v1.y, false)
             + __builtin_amdgcn_cvt_pk_f32_fp8(v2.y, false)
             + __builtin_amdgcn_cvt_pk_f32_fp8(v3.y, false);
        a67 += __builtin_amdgcn_cvt_pk_f32_fp8(v0.y, true)
             + __builtin_amdgcn_cvt_pk_f32_fp8(v1.y, true)
             + __builtin_amdgcn_cvt_pk_f32_fp8(v2.y, true)
             + __builtin_amdgcn_cvt_pk_f32_fp8(v3.y, true);
    }
    float a[8] = {a01[0], a01[1], a23[0], a23[1], a45[0], a45[1], a67[0], a67[1]};
    #pragma unroll
    for (int j = 0; j < 8; j++) {
        a[j] += __shfl_xor(a[j], 16, 64);
        a[j] += __shfl_xor(a[j], 32, 64);
    }
    float inv = 1.f / fmaxf((float)len, 1.f);

    float zf[8] = {bflo(zv.x), bfhi(zv.x), bflo(zv.y), bfhi(zv.y),
                   bflo(zv.z), bfhi(zv.z), bflo(zv.w), bfhi(zv.w)};
    float h[8];
    #pragma unroll
    for (int j = 0; j < 8; j++)
        h[j] = fmaxf(a[j] * inv + zf[j], 0.f);

    float p[3];
    #pragma unroll
    for (int qq = 0; qq < 3; qq++) {
        int q = g4 * 3 + qq;
        float s = 0.f;
        if (q < 11) {
            uint4 ww = *(const uint4*)&wsb[q * 128 + c16 * 8];
            s = h[0] * bflo(ww.x) + h[1] * bfhi(ww.x)
              + h[2] * bflo(ww.y) + h[3] * bfhi(ww.y)
              + h[4] * bflo(ww.z) + h[5] * bfhi(ww.z)
              + h[6] * bflo(ww.w) + h[7] * bfhi(ww.w);
        }
        #pragma unroll
        for (int d = 1; d < 16; d <<= 1)
            s += __shfl_xor(s, d, 64);
        p[qq] = s;
    }
    if (c16 == 0) {
        #pragma unroll
        for (int qq = 0; qq < 3; qq++) {
            int q = g4 * 3 + qq;
            if (q >= 11) continue;
            float val = p[qq] + w[(size_t)node * 16 + q] + cq[q];
            if (q == 0) {
                float al = palpha[0];
                float aa = 1.f / (1.f + expf(-al));
                outF[node] = aa * rrs[node] + (1.f - aa) * val;
            } else {
                outL[(size_t)node * NCRIT + q - 1] = val;
            }
        }
    }
}

extern "C" void kernel_launch(void* const* d_in, const int* in_sizes, int n_in,
                              void* d_out, int out_size, void* d_ws, size_t ws_size,
                              hipStream_t stream) {
    const float* x      = (const float*)d_in[0];
    const int*   ei     = (const int*)d_in[1];
    const float* rrs    = (const float*)d_in[2];
    const float* Wl     = (const float*)d_in[3];
    const float* bl     = (const float*)d_in[4];
    const float* Wr     = (const float*)d_in[5];
    const float* Wres   = (const float*)d_in[6];
    const float* bres   = (const float*)d_in[7];
    const float* wscore = (const float*)d_in[8];
    const float* bscore = (const float*)d_in[9];
    const float* wcrit  = (const float*)d_in[10];
    const float* bcrit  = (const float*)d_in[11];
    const float* alpha  = (const float*)d_in[12];

    int N = in_sizes[0] / DIN;
    int E = in_sizes[1] / 2;
    const int* srcv = ei;
    const int* dstv = ei + E;

    int nB = (N + 511) >> BSH;
    // room for x16 padding: up to 512 nodes * 15 pad + 2*avg load
    int capb = (int)alignup((size_t)(E / (nB > 0 ? nB : 1)) * 2 + 512 * 16 + 256, 16);

    char* p = (char*)d_ws;
    int* bcnt  = (int*)p; p += alignup((size_t)nB * 16 * 4, 256);
    int* bpool = (int*)p; p += alignup((size_t)nB * capb * 4, 256);
    int2* ocnt = (int2*)p; p += alignup((size_t)N * 8, 256);
    int* sidx  = (int*)p; p += alignup((size_t)nB * capb * 4, 256);
    bf16* WcatT = (bf16*)p; p += alignup((size_t)32 * 272 * 16, 256);
    unsigned char* yq = (unsigned char*)p; p += alignup((size_t)(N + 1) * HDIM, 256);
    bf16* z    = (bf16*)p; p += alignup((size_t)N * HDIM * 2, 256);
    float* w   = (float*)p; p += alignup((size_t)N * 16 * 4, 256);
    float* cq  = (float*)p; p += 256;

    hipMemsetAsync(bcnt, 0, (size_t)nB * 16 * 4, stream);

    k_bucket2<<<81 + (E + EPB - 1) / EPB, 256, 0, stream>>>(
        srcv, dstv, E, bcnt, bpool, capb, nB, Wl, Wr, Wres, wscore, wcrit,
        bres, bscore, bcrit, WcatT, cq);
    k_fin<<<nB, 256, 0, stream>>>(bcnt, bpool, capb, N, ocnt, sidx, yq);

    k_gemm<<<256, 512, 0, stream>>>(x, WcatT, N, yq, z, w, bl);

    float* outF = (float*)d_out;
    float* outL = outF + N;
    k_gather<<<(N + 3) / 4, 256, 0, stream>>>(yq, z, w, cq, ocnt, sidx,
                                              wscore, wcrit, rrs, alpha, N, outF, outL);
}

// Round 25
// 177.094 us; speedup vs baseline: 1.0143x; 1.0143x over previous
//
#include <hip/hip_runtime.h>
#include <math.h>

#define DIN 256
#define HDIM 128
#define NCRIT 10
#define BSH 9
#define EPB 4096

typedef __bf16 bf16;
typedef bf16 bf16x8 __attribute__((ext_vector_type(8)));
typedef float f32x4 __attribute__((ext_vector_type(4)));
typedef float f32x2 __attribute__((ext_vector_type(2)));

static inline size_t alignup(size_t x, size_t a) { return (x + a - 1) & ~(a - 1); }

__device__ inline float bflo(unsigned v) { return __uint_as_float(v << 16); }
__device__ inline float bfhi(unsigned v) { return __uint_as_float(v & 0xffff0000u); }

__device__ inline bf16x8 cvt8(float4 v0, float4 v1) {
    bf16x8 w;
    w[0] = (bf16)v0.x; w[1] = (bf16)v0.y; w[2] = (bf16)v0.z; w[3] = (bf16)v0.w;
    w[4] = (bf16)v1.x; w[5] = (bf16)v1.y; w[6] = (bf16)v1.z; w[7] = (bf16)v1.w;
    return w;
}

__device__ inline void gl_lds16(const void* g, void* l) {
    __builtin_amdgcn_global_load_lds(
        (const __attribute__((address_space(1))) unsigned*)g,
        (__attribute__((address_space(3))) unsigned*)l, 16, 0, 0);
}

// ---------- k1: wconv(0..63) + Wcomb(64..79) + cq(80) || block-staged bucket append ----------
// bpool entries packed: (src << 9) | (dst & 511)
__global__ __launch_bounds__(256) void k_bucket2(
    const int* __restrict__ src, const int* __restrict__ dst, int E,
    int* __restrict__ bcnt, int* __restrict__ bpool, int capb, int nB,
    const float* __restrict__ Wl, const float* __restrict__ Wr,
    const float* __restrict__ Wres,
    const float* __restrict__ wscore, const float* __restrict__ wcrit,
    const float* __restrict__ bres, const float* __restrict__ bscore,
    const float* __restrict__ bcrit,
    bf16* __restrict__ WcatT, float* __restrict__ cq)
{
    int t = threadIdx.x;
    int b = blockIdx.x;
    if (b < 64) {
        int base = (b * 256 + t) * 4;
        int r = base >> 8;
        int c0 = base & 255;
        const float* W = (r < 128) ? Wl : Wr;
        float4 v = *(const float4*)&W[(size_t)(r & 127) * 256 + c0];
        bf16 o[4] = {(bf16)v.x, (bf16)v.y, (bf16)v.z, (bf16)v.w};
        char* d = (char*)WcatT + ((((size_t)(c0 >> 3) * 272 + r) << 4) + ((c0 & 7) << 1));
        *(uint2*)d = *(const uint2*)o;
        return;
    } else if (b < 80) {
        int q = b - 64;
        int k = t;
        float s = 0.f;
        if (q < 11) {
            const float* wepi = (q == 0) ? wscore : &wcrit[(size_t)(q - 1) * HDIM];
            for (int c = 0; c < HDIM; ++c)
                s += wepi[c] * Wres[(size_t)c * 256 + k];
        }
        char* d = (char*)WcatT + ((((size_t)(k >> 3) * 272 + 256 + q) << 4) + ((k & 7) << 1));
        *(bf16*)d = (bf16)s;
        return;
    } else if (b == 80) {
        if (t < 11) {
            const float* wepi = (t == 0) ? wscore : &wcrit[(size_t)(t - 1) * HDIM];
            float s = 0.f;
            for (int c = 0; c < HDIM; ++c) s += bres[c] * wepi[c];
            cq[t] = s + ((t == 0) ? bscore[0] : bcrit[t - 1]);
        }
        return;
    }

    __shared__ int lcnt[256], lbase[256], lcur[256], gbase[256];
    __shared__ int stage[EPB];

    int blk = b - 81;
    int base = blk * EPB;
    int m = min(EPB, E - base);
    if (m <= 0) return;

    lcnt[t] = 0;
    __syncthreads();
    for (int i = t; i < m; i += 256)
        atomicAdd(&lcnt[dst[base + i] >> BSH], 1);
    __syncthreads();
    int c0 = lcnt[t];
    for (int d = 1; d < 256; d <<= 1) {
        int a0 = lcnt[t];
        int b0 = (t >= d) ? lcnt[t - d] : 0;
        __syncthreads();
        lcnt[t] = a0 + b0;
        __syncthreads();
    }
    int e0 = lcnt[t] - c0;
    lbase[t] = e0;
    lcur[t] = e0;
    if (t < nB && c0 > 0) gbase[t] = atomicAdd(&bcnt[t * 16], c0);
    __syncthreads();
    for (int i = t; i < m; i += 256) {
        int s2 = src[base + i], d = dst[base + i];
        int bk = d >> BSH;
        int pos = atomicAdd(&lcur[bk], 1);
        stage[pos] = (s2 << BSH) | (d & 511);
    }
    __syncthreads();
    int wv = t >> 6, lane = t & 63;
    for (int bk = wv; bk < nB; bk += 4) {
        int lb = lbase[bk];
        int cb = lcnt[bk] - lb;
        if (cb == 0) continue;
        int gb = gbase[bk];
        int* dstp = bpool + (size_t)bk * capb + gb;
        for (int j = lane; j < cb && gb + j < capb; j += 64)
            dstp[j] = stage[lb + j];
    }
}

// ---------- k2: per-bucket finalize (x4-padded lists; pads -> zero-row index n) ----------
__global__ __launch_bounds__(256) void k_fin(const int* __restrict__ bcnt,
                                             const int* __restrict__ bpool, int capb,
                                             int n, int2* __restrict__ ocnt,
                                             int* __restrict__ sidx,
                                             unsigned char* __restrict__ yq) {
    __shared__ int lcnt[512], lcur[512];
    int b = blockIdx.x, t = threadIdx.x;
    int m = min(bcnt[b * 16], capb);
    const int* ep = bpool + (size_t)b * capb;

    if (b == 0 && t < 8)
        *(uint4*)(yq + (size_t)n * 128 + t * 16) = make_uint4(0, 0, 0, 0);

    lcnt[t] = 0; lcnt[t + 256] = 0;
    __syncthreads();
    for (int i = t; i < m; i += 256)
        atomicAdd(&lcnt[ep[i] & 511], 1);
    __syncthreads();
    int c0 = lcnt[t], c1 = lcnt[t + 256];
    int p0 = (c0 + 3) & ~3, p1 = (c1 + 3) & ~3;
    __syncthreads();
    lcnt[t] = p0; lcnt[t + 256] = p1;
    __syncthreads();
    for (int d = 1; d < 512; d <<= 1) {
        int a0 = lcnt[t], a1 = lcnt[t + 256];
        int b0 = (t >= d) ? lcnt[t - d] : 0;
        int b1 = ((t + 256) >= d) ? lcnt[t + 256 - d] : 0;
        __syncthreads();
        lcnt[t] = a0 + b0; lcnt[t + 256] = a1 + b1;
        __syncthreads();
    }
    int e0 = lcnt[t] - p0, e1 = lcnt[t + 256] - p1;
    int nbase = b << BSH;
    int sbase = b * capb;
    lcur[t] = e0; lcur[t + 256] = e1;
    int n0 = nbase + t, n1 = nbase + t + 256;
    if (n0 < n) ocnt[n0] = make_int2(sbase + e0, c0);
    if (n1 < n) ocnt[n1] = make_int2(sbase + e1, c1);
    for (int j = c0; j < p0; j++) sidx[sbase + e0 + j] = n;
    for (int j = c1; j < p1; j++) sidx[sbase + e1 + j] = n;
    __syncthreads();
    for (int i = t; i < m; i += 256) {
        int e = ep[i];
        int pos = atomicAdd(&lcur[e & 511], 1);
        sidx[sbase + pos] = (int)(((unsigned)e) >> BSH);
    }
}

// ---------- k3: barrier-free GEMM (z' = zr + bl folded) ----------
__global__ __launch_bounds__(512) void k_gemm(
    const float* __restrict__ x, const bf16* __restrict__ WcatT, int n,
    unsigned char* __restrict__ yq, bf16* __restrict__ z, float* __restrict__ w,
    const float* __restrict__ bl)
{
    __shared__ __align__(16) char smem[147456];
    int t = threadIdx.x;
    int wv = t >> 6, lane = t & 63;
    int l15 = lane & 15, kq = lane >> 4;

    {
        int cbase0 = wv * 64;
        #pragma unroll
        for (int i = 0; i < 17; i++) {
            int cbase = i * 512 + cbase0;
            gl_lds16((const char*)WcatT + (((size_t)cbase + lane) << 4),
                     smem + ((size_t)cbase << 4));
        }
    }
    __syncthreads();

    char* scr = smem + 139264 + wv * 1024;
    int rrow = lane >> 2, rc4 = (lane & 3) * 4;

    int nTiles = (n + 127) >> 7;
    for (int tile = blockIdx.x; tile < nTiles; tile += gridDim.x) {
        int rowb = tile * 128 + wv * 16;
        int myrow = rowb + l15;
        const float* ap = x + (size_t)(myrow < n ? myrow : (n - 1)) * 256 + kq * 8;

        float4 xa[8], xb[8];
        #pragma unroll
        for (int s = 0; s < 8; s++) {
            xa[s] = *(const float4*)(ap + s * 32);
            xb[s] = *(const float4*)(ap + s * 32 + 4);
        }

        f32x4 acc[17];
        #pragma unroll
        for (int C = 0; C < 17; C++) acc[C] = (f32x4){0.f, 0.f, 0.f, 0.f};

        #pragma unroll
        for (int s = 0; s < 8; s++) {
            bf16x8 afr = cvt8(xa[s], xb[s]);
            int sbase = ((s * 4 + kq) * 272 + l15) << 4;
            #pragma unroll
            for (int C = 0; C < 17; C++) {
                bf16x8 b = *(const bf16x8*)(smem + sbase + C * 256);
                acc[C] = __builtin_amdgcn_mfma_f32_16x16x32_bf16(afr, b, acc[C], 0, 0, 0);
            }
        }

        int gr = rowb + rrow;
        bool ok = gr < n;
        #pragma unroll
        for (int C = 0; C < 17; C++) {
            #pragma unroll
            for (int j = 0; j < 4; j++)
                *(float*)(scr + ((((kq << 2) + j) * 16 + l15) << 2)) = acc[C][j];
            f32x4 vv = *(const f32x4*)(scr + ((rrow * 16 + rc4) << 2));
            if (C < 8) {
                unsigned pk = (unsigned)__builtin_amdgcn_cvt_pk_fp8_f32(vv[0], vv[1], 0, false);
                pk = (unsigned)__builtin_amdgcn_cvt_pk_fp8_f32(vv[2], vv[3], pk, true);
                if (ok) *(unsigned*)(yq + (size_t)gr * 128 + C * 16 + rc4) = pk;
            } else if (C < 16) {
                float4 blv = *(const float4*)&bl[(C - 8) * 16 + rc4];
                bf16 o[4] = {(bf16)(vv[0] + blv.x), (bf16)(vv[1] + blv.y),
                             (bf16)(vv[2] + blv.z), (bf16)(vv[3] + blv.w)};
                if (ok) *(uint2*)((char*)z + (size_t)gr * 256 + (C - 8) * 32 + rc4 * 2) =
                            *(const uint2*)o;
            } else {
                if (ok) *(f32x4*)(w + (size_t)gr * 16 + rc4) = vv;
            }
        }
    }
}

// ---------- k4: gather, 8B/lane, mask-free x4-padded loops, packed ocnt ----------
__global__ __launch_bounds__(256) void k_gather(
    const unsigned char* __restrict__ yq, const bf16* __restrict__ z,
    const float* __restrict__ w, const float* __restrict__ cq,
    const int2* __restrict__ ocnt, const int* __restrict__ sidx,
    const float* __restrict__ wscore, const float* __restrict__ wcrit,
    const float* __restrict__ rrs, const float* __restrict__ palpha,
    int n, float* __restrict__ outF, float* __restrict__ outL)
{
    __shared__ bf16 wsb[11 * 128];
    int t = threadIdx.x;
    for (int i = t; i < 11 * 128; i += 256) {
        int q = i >> 7, c = i & 127;
        wsb[i] = (bf16)((q == 0) ? wscore[c] : wcrit[(size_t)(q - 1) * HDIM + c]);
    }
    __syncthreads();

    int node = blockIdx.x * 4 + (t >> 6);
    if (node >= n) return;
    int lane = t & 63, g4 = lane >> 4, c16 = lane & 15;

    int2 oc = ocnt[node];                 // single dependent load: {beg, len}
    uint4 zv = *(const uint4*)((const char*)z + (size_t)node * 256 + c16 * 16);

    const unsigned char* ybase = yq + c16 * 8;
    int beg = oc.x, len = oc.y;
    int lenp = (len + 3) & ~3;
    const int* sp = sidx + beg;

    f32x2 a01 = {0.f, 0.f}, a23 = {0.f, 0.f}, a45 = {0.f, 0.f}, a67 = {0.f, 0.f};
    int e = 0;
    for (; e + 16 <= lenp; e += 16) {
        int4 iv = *(const int4*)&sp[e + g4 * 4];
        uint2 v0 = *(const uint2*)(ybase + ((size_t)(unsigned)iv.x << 7));
        uint2 v1 = *(const uint2*)(ybase + ((size_t)(unsigned)iv.y << 7));
        uint2 v2 = *(const uint2*)(ybase + ((size_t)(unsigned)iv.z << 7));
        uint2 v3 = *(const uint2*)(ybase + ((size_t)(unsigned)iv.w << 7));
        a01 += __builtin_amdgcn_cvt_pk_f32_fp8(v0.x, false)
             + __builtin_amdgcn_cvt_pk_f32_fp8(v1.x, false)
             + __builtin_amdgcn_cvt_pk_f32_fp8(v2.x, false)
             + __builtin_amdgcn_cvt_pk_f32_fp8(v3.x, false);
        a23 += __builtin_amdgcn_cvt_pk_f32_fp8(v0.x, true)
             + __builtin_amdgcn_cvt_pk_f32_fp8(v1.x, true)
             + __builtin_amdgcn_cvt_pk_f32_fp8(v2.x, true)
             + __builtin_amdgcn_cvt_pk_f32_fp8(v3.x, true);
        a45 += __builtin_amdgcn_cvt_pk_f32_fp8(v0.y, false)
             + __builtin_amdgcn_cvt_pk_f32_fp8(v1.y, false)
             + __builtin_amdgcn_cvt_pk_f32_fp8(v2.y, false)
             + __builtin_amdgcn_cvt_pk_f32_fp8(v3.y, false);
        a67 += __builtin_amdgcn_cvt_pk_f32_fp8(v0.y, true)
             + __builtin_amdgcn_cvt_pk_f32_fp8(v1.y, true)
             + __builtin_amdgcn_cvt_pk_f32_fp8(v2.y, true)
             + __builtin_amdgcn_cvt_pk_f32_fp8(v3.y, true);
    }
    if (lenp & 8) {
        int2 iv = *(const int2*)&sp[e + g4 * 2];
        uint2 v0 = *(const uint2*)(ybase + ((size_t)(unsigned)iv.x << 7));
        uint2 v1 = *(const uint2*)(ybase + ((size_t)(unsigned)iv.y << 7));
        a01 += __builtin_amdgcn_cvt_pk_f32_fp8(v0.x, false)
             + __builtin_amdgcn_cvt_pk_f32_fp8(v1.x, false);
        a23 += __builtin_amdgcn_cvt_pk_f32_fp8(v0.x, true)
             + __builtin_amdgcn_cvt_pk_f32_fp8(v1.x, true);
        a45 += __builtin_amdgcn_cvt_pk_f32_fp8(v0.y, false)
             + __builtin_amdgcn_cvt_pk_f32_fp8(v1.y, false);
        a67 += __builtin_amdgcn_cvt_pk_f32_fp8(v0.y, true)
             + __builtin_amdgcn_cvt_pk_f32_fp8(v1.y, true);
        e += 8;
    }
    if (lenp & 4) {
        int i0 = sp[e + g4];
        uint2 v = *(const uint2*)(ybase + ((size_t)(unsigned)i0 << 7));
        a01 += __builtin_amdgcn_cvt_pk_f32_fp8(v.x, false);
        a23 += __builtin_amdgcn_cvt_pk_f32_fp8(v.x, true);
        a45 += __builtin_amdgcn_cvt_pk_f32_fp8(v.y, false);
        a67 += __builtin_amdgcn_cvt_pk_f32_fp8(v.y, true);
    }
    float a[8] = {a01[0], a01[1], a23[0], a23[1], a45[0], a45[1], a67[0], a67[1]};
    #pragma unroll
    for (int j = 0; j < 8; j++) {
        a[j] += __shfl_xor(a[j], 16, 64);
        a[j] += __shfl_xor(a[j], 32, 64);
    }
    float inv = 1.f / fmaxf((float)len, 1.f);

    float zf[8] = {bflo(zv.x), bfhi(zv.x), bflo(zv.y), bfhi(zv.y),
                   bflo(zv.z), bfhi(zv.z), bflo(zv.w), bfhi(zv.w)};
    float h[8];
    #pragma unroll
    for (int j = 0; j < 8; j++)
        h[j] = fmaxf(a[j] * inv + zf[j], 0.f);

    float p[3];
    #pragma unroll
    for (int qq = 0; qq < 3; qq++) {
        int q = g4 * 3 + qq;
        float s = 0.f;
        if (q < 11) {
            uint4 ww = *(const uint4*)&wsb[q * 128 + c16 * 8];
            s = h[0] * bflo(ww.x) + h[1] * bfhi(ww.x)
              + h[2] * bflo(ww.y) + h[3] * bfhi(ww.y)
              + h[4] * bflo(ww.z) + h[5] * bfhi(ww.z)
              + h[6] * bflo(ww.w) + h[7] * bfhi(ww.w);
        }
        #pragma unroll
        for (int d = 1; d < 16; d <<= 1)
            s += __shfl_xor(s, d, 64);
        p[qq] = s;
    }
    if (c16 == 0) {
        #pragma unroll
        for (int qq = 0; qq < 3; qq++) {
            int q = g4 * 3 + qq;
            if (q >= 11) continue;
            float val = p[qq] + w[(size_t)node * 16 + q] + cq[q];
            if (q == 0) {
                float al = palpha[0];
                float aa = 1.f / (1.f + expf(-al));
                outF[node] = aa * rrs[node] + (1.f - aa) * val;
            } else {
                outL[(size_t)node * NCRIT + q - 1] = val;
            }
        }
    }
}

extern "C" void kernel_launch(void* const* d_in, const int* in_sizes, int n_in,
                              void* d_out, int out_size, void* d_ws, size_t ws_size,
                              hipStream_t stream) {
    const float* x      = (const float*)d_in[0];
    const int*   ei     = (const int*)d_in[1];
    const float* rrs    = (const float*)d_in[2];
    const float* Wl     = (const float*)d_in[3];
    const float* bl     = (const float*)d_in[4];
    const float* Wr     = (const float*)d_in[5];
    const float* Wres   = (const float*)d_in[6];
    const float* bres   = (const float*)d_in[7];
    const float* wscore = (const float*)d_in[8];
    const float* bscore = (const float*)d_in[9];
    const float* wcrit  = (const float*)d_in[10];
    const float* bcrit  = (const float*)d_in[11];
    const float* alpha  = (const float*)d_in[12];

    int N = in_sizes[0] / DIN;
    int E = in_sizes[1] / 2;
    const int* srcv = ei;
    const int* dstv = ei + E;

    int nB = (N + 511) >> BSH;
    int capb = (int)alignup((size_t)(E / (nB > 0 ? nB : 1)) * 2 + 512 * 4 + 256, 16);

    char* p = (char*)d_ws;
    int* bcnt  = (int*)p; p += alignup((size_t)nB * 16 * 4, 256);
    int* bpool = (int*)p; p += alignup((size_t)nB * capb * 4, 256);
    int2* ocnt = (int2*)p; p += alignup((size_t)N * 8, 256);
    int* sidx  = (int*)p; p += alignup((size_t)nB * capb * 4, 256);
    bf16* WcatT = (bf16*)p; p += alignup((size_t)32 * 272 * 16, 256);
    unsigned char* yq = (unsigned char*)p; p += alignup((size_t)(N + 1) * HDIM, 256);
    bf16* z    = (bf16*)p; p += alignup((size_t)N * HDIM * 2, 256);
    float* w   = (float*)p; p += alignup((size_t)N * 16 * 4, 256);
    float* cq  = (float*)p; p += 256;

    hipMemsetAsync(bcnt, 0, (size_t)nB * 16 * 4, stream);

    k_bucket2<<<81 + (E + EPB - 1) / EPB, 256, 0, stream>>>(
        srcv, dstv, E, bcnt, bpool, capb, nB, Wl, Wr, Wres, wscore, wcrit,
        bres, bscore, bcrit, WcatT, cq);
    k_fin<<<nB, 256, 0, stream>>>(bcnt, bpool, capb, N, ocnt, sidx, yq);

    k_gemm<<<256, 512, 0, stream>>>(x, WcatT, N, yq, z, w, bl);

    float* outF = (float*)d_out;
    float* outL = outF + N;
    k_gather<<<(N + 3) / 4, 256, 0, stream>>>(yq, z, w, cq, ocnt, sidx,
                                              wscore, wcrit, rrs, alpha, N, outF, outL);
}

// Round 26
// 159.331 us; speedup vs baseline: 1.1274x; 1.1115x over previous
//
#include <hip/hip_runtime.h>
#include <math.h>

#define DIN 256
#define HDIM 128
#define NCRIT 10
#define BSH 9
#define EPB 4096

typedef __bf16 bf16;
typedef bf16 bf16x8 __attribute__((ext_vector_type(8)));
typedef float f32x4 __attribute__((ext_vector_type(4)));
typedef float f32x2 __attribute__((ext_vector_type(2)));

static inline size_t alignup(size_t x, size_t a) { return (x + a - 1) & ~(a - 1); }

__device__ inline float bflo(unsigned v) { return __uint_as_float(v << 16); }
__device__ inline float bfhi(unsigned v) { return __uint_as_float(v & 0xffff0000u); }

__device__ inline bf16x8 cvt8(float4 v0, float4 v1) {
    bf16x8 w;
    w[0] = (bf16)v0.x; w[1] = (bf16)v0.y; w[2] = (bf16)v0.z; w[3] = (bf16)v0.w;
    w[4] = (bf16)v1.x; w[5] = (bf16)v1.y; w[6] = (bf16)v1.z; w[7] = (bf16)v1.w;
    return w;
}

__device__ inline void gl_lds16(const void* g, void* l) {
    __builtin_amdgcn_global_load_lds(
        (const __attribute__((address_space(1))) unsigned*)g,
        (__attribute__((address_space(3))) unsigned*)l, 16, 0, 0);
}

// ---------- k1: wconv(0..63) + Wcomb(64..79) + cq(80) || block-staged bucket append ----------
// bpool entries packed: (src << 9) | (dst & 511)
__global__ __launch_bounds__(256) void k_bucket2(
    const int* __restrict__ src, const int* __restrict__ dst, int E,
    int* __restrict__ bcnt, int* __restrict__ bpool, int capb, int nB,
    const float* __restrict__ Wl, const float* __restrict__ Wr,
    const float* __restrict__ Wres,
    const float* __restrict__ wscore, const float* __restrict__ wcrit,
    const float* __restrict__ bres, const float* __restrict__ bscore,
    const float* __restrict__ bcrit,
    bf16* __restrict__ WcatT, float* __restrict__ cq)
{
    int t = threadIdx.x;
    int b = blockIdx.x;
    if (b < 64) {
        int base = (b * 256 + t) * 4;
        int r = base >> 8;
        int c0 = base & 255;
        const float* W = (r < 128) ? Wl : Wr;
        float4 v = *(const float4*)&W[(size_t)(r & 127) * 256 + c0];
        bf16 o[4] = {(bf16)v.x, (bf16)v.y, (bf16)v.z, (bf16)v.w};
        char* d = (char*)WcatT + ((((size_t)(c0 >> 3) * 272 + r) << 4) + ((c0 & 7) << 1));
        *(uint2*)d = *(const uint2*)o;
        return;
    } else if (b < 80) {
        int q = b - 64;
        int k = t;
        float s = 0.f;
        if (q < 11) {
            const float* wepi = (q == 0) ? wscore : &wcrit[(size_t)(q - 1) * HDIM];
            for (int c = 0; c < HDIM; ++c)
                s += wepi[c] * Wres[(size_t)c * 256 + k];
        }
        char* d = (char*)WcatT + ((((size_t)(k >> 3) * 272 + 256 + q) << 4) + ((k & 7) << 1));
        *(bf16*)d = (bf16)s;
        return;
    } else if (b == 80) {
        if (t < 11) {
            const float* wepi = (t == 0) ? wscore : &wcrit[(size_t)(t - 1) * HDIM];
            float s = 0.f;
            for (int c = 0; c < HDIM; ++c) s += bres[c] * wepi[c];
            cq[t] = s + ((t == 0) ? bscore[0] : bcrit[t - 1]);
        }
        return;
    }

    __shared__ int lcnt[256], lbase[256], lcur[256], gbase[256];
    __shared__ int stage[EPB];

    int blk = b - 81;
    int base = blk * EPB;
    int m = min(EPB, E - base);
    if (m <= 0) return;

    lcnt[t] = 0;
    __syncthreads();
    for (int i = t; i < m; i += 256)
        atomicAdd(&lcnt[dst[base + i] >> BSH], 1);
    __syncthreads();
    int c0 = lcnt[t];
    for (int d = 1; d < 256; d <<= 1) {
        int a0 = lcnt[t];
        int b0 = (t >= d) ? lcnt[t - d] : 0;
        __syncthreads();
        lcnt[t] = a0 + b0;
        __syncthreads();
    }
    int e0 = lcnt[t] - c0;
    lbase[t] = e0;
    lcur[t] = e0;
    if (t < nB && c0 > 0) gbase[t] = atomicAdd(&bcnt[t * 16], c0);
    __syncthreads();
    for (int i = t; i < m; i += 256) {
        int s2 = src[base + i], d = dst[base + i];
        int bk = d >> BSH;
        int pos = atomicAdd(&lcur[bk], 1);
        stage[pos] = (s2 << BSH) | (d & 511);
    }
    __syncthreads();
    int wv = t >> 6, lane = t & 63;
    for (int bk = wv; bk < nB; bk += 4) {
        int lb = lbase[bk];
        int cb = lcnt[bk] - lb;
        if (cb == 0) continue;
        int gb = gbase[bk];
        int* dstp = bpool + (size_t)bk * capb + gb;
        for (int j = lane; j < cb && gb + j < capb; j += 64)
            dstp[j] = stage[lb + j];
    }
}

// ---------- k2: fused fin (blocks [0,nB)) || barrier-free GEMM (blocks [nB,nB+256)) ----------
__global__ __launch_bounds__(512) void k_fingemm(
    const int* __restrict__ bcnt, const int* __restrict__ bpool, int capb, int nB,
    int2* __restrict__ ocnt, int* __restrict__ sidx,
    const float* __restrict__ x, const bf16* __restrict__ WcatT, int n,
    unsigned char* __restrict__ yq, bf16* __restrict__ z, float* __restrict__ w,
    const float* __restrict__ bl)
{
    __shared__ __align__(16) char smem[147456];
    int t = threadIdx.x;
    int b = blockIdx.x;

    if (b < nB) {
        // ---- fin path (512 threads) ----
        int* lcnt = (int*)smem;             // [512]
        int* lcur = (int*)smem + 512;       // [512]
        int m = min(bcnt[b * 16], capb);
        const int* ep = bpool + (size_t)b * capb;

        if (b == 0 && t < 8)
            *(uint4*)(yq + (size_t)n * 128 + t * 16) = make_uint4(0, 0, 0, 0);

        lcnt[t] = 0;
        __syncthreads();
        for (int i = t; i < m; i += 512)
            atomicAdd(&lcnt[ep[i] & 511], 1);
        __syncthreads();
        int c0 = lcnt[t];
        int p0 = (c0 + 3) & ~3;
        __syncthreads();
        lcnt[t] = p0;
        __syncthreads();
        for (int d = 1; d < 512; d <<= 1) {
            int a0 = lcnt[t];
            int b0 = (t >= d) ? lcnt[t - d] : 0;
            __syncthreads();
            lcnt[t] = a0 + b0;
            __syncthreads();
        }
        int e0 = lcnt[t] - p0;
        int nbase = b << BSH;
        int sbase = b * capb;
        lcur[t] = e0;
        int node = nbase + t;
        if (node < n) ocnt[node] = make_int2(sbase + e0, c0);
        for (int j = c0; j < p0; j++) sidx[sbase + e0 + j] = n;
        __syncthreads();
        for (int i = t; i < m; i += 512) {
            int e = ep[i];
            int pos = atomicAdd(&lcur[e & 511], 1);
            sidx[sbase + pos] = (int)(((unsigned)e) >> BSH);
        }
        return;
    }

    // ---- gemm path ----
    int gb = b - nB;                        // 0..255
    int wv = t >> 6, lane = t & 63;
    int l15 = lane & 15, kq = lane >> 4;

    {
        int cbase0 = wv * 64;
        #pragma unroll
        for (int i = 0; i < 17; i++) {
            int cbase = i * 512 + cbase0;
            gl_lds16((const char*)WcatT + (((size_t)cbase + lane) << 4),
                     smem + ((size_t)cbase << 4));
        }
    }
    __syncthreads();

    char* scr = smem + 139264 + wv * 1024;
    int rrow = lane >> 2, rc4 = (lane & 3) * 4;

    int nTiles = (n + 127) >> 7;
    for (int tile = gb; tile < nTiles; tile += 256) {
        int rowb = tile * 128 + wv * 16;
        int myrow = rowb + l15;
        const float* ap = x + (size_t)(myrow < n ? myrow : (n - 1)) * 256 + kq * 8;

        float4 xa[8], xb[8];
        #pragma unroll
        for (int s = 0; s < 8; s++) {
            xa[s] = *(const float4*)(ap + s * 32);
            xb[s] = *(const float4*)(ap + s * 32 + 4);
        }

        f32x4 acc[17];
        #pragma unroll
        for (int C = 0; C < 17; C++) acc[C] = (f32x4){0.f, 0.f, 0.f, 0.f};

        #pragma unroll
        for (int s = 0; s < 8; s++) {
            bf16x8 afr = cvt8(xa[s], xb[s]);
            int sbase = ((s * 4 + kq) * 272 + l15) << 4;
            #pragma unroll
            for (int C = 0; C < 17; C++) {
                bf16x8 bb = *(const bf16x8*)(smem + sbase + C * 256);
                acc[C] = __builtin_amdgcn_mfma_f32_16x16x32_bf16(afr, bb, acc[C], 0, 0, 0);
            }
        }

        int gr = rowb + rrow;
        bool ok = gr < n;
        #pragma unroll
        for (int C = 0; C < 17; C++) {
            #pragma unroll
            for (int j = 0; j < 4; j++)
                *(float*)(scr + ((((kq << 2) + j) * 16 + l15) << 2)) = acc[C][j];
            f32x4 vv = *(const f32x4*)(scr + ((rrow * 16 + rc4) << 2));
            if (C < 8) {
                unsigned pk = (unsigned)__builtin_amdgcn_cvt_pk_fp8_f32(vv[0], vv[1], 0, false);
                pk = (unsigned)__builtin_amdgcn_cvt_pk_fp8_f32(vv[2], vv[3], pk, true);
                if (ok) *(unsigned*)(yq + (size_t)gr * 128 + C * 16 + rc4) = pk;
            } else if (C < 16) {
                float4 blv = *(const float4*)&bl[(C - 8) * 16 + rc4];
                bf16 o[4] = {(bf16)(vv[0] + blv.x), (bf16)(vv[1] + blv.y),
                             (bf16)(vv[2] + blv.z), (bf16)(vv[3] + blv.w)};
                if (ok) *(uint2*)((char*)z + (size_t)gr * 256 + (C - 8) * 32 + rc4 * 2) =
                            *(const uint2*)o;
            } else {
                if (ok) *(f32x4*)(w + (size_t)gr * 16 + rc4) = vv;
            }
        }
    }
}

// ---------- k3: gather, 8B/lane, mask-free x4-padded loops, packed ocnt ----------
__global__ __launch_bounds__(256) void k_gather(
    const unsigned char* __restrict__ yq, const bf16* __restrict__ z,
    const float* __restrict__ w, const float* __restrict__ cq,
    const int2* __restrict__ ocnt, const int* __restrict__ sidx,
    const float* __restrict__ wscore, const float* __restrict__ wcrit,
    const float* __restrict__ rrs, const float* __restrict__ palpha,
    int n, float* __restrict__ outF, float* __restrict__ outL)
{
    __shared__ bf16 wsb[11 * 128];
    int t = threadIdx.x;
    for (int i = t; i < 11 * 128; i += 256) {
        int q = i >> 7, c = i & 127;
        wsb[i] = (bf16)((q == 0) ? wscore[c] : wcrit[(size_t)(q - 1) * HDIM + c]);
    }
    __syncthreads();

    int node = blockIdx.x * 4 + (t >> 6);
    if (node >= n) return;
    int lane = t & 63, g4 = lane >> 4, c16 = lane & 15;

    int2 oc = ocnt[node];
    uint4 zv = *(const uint4*)((const char*)z + (size_t)node * 256 + c16 * 16);

    const unsigned char* ybase = yq + c16 * 8;
    int beg = oc.x, len = oc.y;
    int lenp = (len + 3) & ~3;
    const int* sp = sidx + beg;

    f32x2 a01 = {0.f, 0.f}, a23 = {0.f, 0.f}, a45 = {0.f, 0.f}, a67 = {0.f, 0.f};
    int e = 0;
    for (; e + 16 <= lenp; e += 16) {
        int4 iv = *(const int4*)&sp[e + g4 * 4];
        uint2 v0 = *(const uint2*)(ybase + ((size_t)(unsigned)iv.x << 7));
        uint2 v1 = *(const uint2*)(ybase + ((size_t)(unsigned)iv.y << 7));
        uint2 v2 = *(const uint2*)(ybase + ((size_t)(unsigned)iv.z << 7));
        uint2 v3 = *(const uint2*)(ybase + ((size_t)(unsigned)iv.w << 7));
        a01 += __builtin_amdgcn_cvt_pk_f32_fp8(v0.x, false)
             + __builtin_amdgcn_cvt_pk_f32_fp8(v1.x, false)
             + __builtin_amdgcn_cvt_pk_f32_fp8(v2.x, false)
             + __builtin_amdgcn_cvt_pk_f32_fp8(v3.x, false);
        a23 += __builtin_amdgcn_cvt_pk_f32_fp8(v0.x, true)
             + __builtin_amdgcn_cvt_pk_f32_fp8(v1.x, true)
             + __builtin_amdgcn_cvt_pk_f32_fp8(v2.x, true)
             + __builtin_amdgcn_cvt_pk_f32_fp8(v3.x, true);
        a45 += __builtin_amdgcn_cvt_pk_f32_fp8(v0.y, false)
             + __builtin_amdgcn_cvt_pk_f32_fp8(v1.y, false)
             + __builtin_amdgcn_cvt_pk_f32_fp8(v2.y, false)
             + __builtin_amdgcn_cvt_pk_f32_fp8(v3.y, false);
        a67 += __builtin_amdgcn_cvt_pk_f32_fp8(v0.y, true)
             + __builtin_amdgcn_cvt_pk_f32_fp8(v1.y, true)
             + __builtin_amdgcn_cvt_pk_f32_fp8(v2.y, true)
             + __builtin_amdgcn_cvt_pk_f32_fp8(v3.y, true);
    }
    if (lenp & 8) {
        int2 iv = *(const int2*)&sp[e + g4 * 2];
        uint2 v0 = *(const uint2*)(ybase + ((size_t)(unsigned)iv.x << 7));
        uint2 v1 = *(const uint2*)(ybase + ((size_t)(unsigned)iv.y << 7));
        a01 += __builtin_amdgcn_cvt_pk_f32_fp8(v0.x, false)
             + __builtin_amdgcn_cvt_pk_f32_fp8(v1.x, false);
        a23 += __builtin_amdgcn_cvt_pk_f32_fp8(v0.x, true)
             + __builtin_amdgcn_cvt_pk_f32_fp8(v1.x, true);
        a45 += __builtin_amdgcn_cvt_pk_f32_fp8(v0.y, false)
             + __builtin_amdgcn_cvt_pk_f32_fp8(v1.y, false);
        a67 += __builtin_amdgcn_cvt_pk_f32_fp8(v0.y, true)
             + __builtin_amdgcn_cvt_pk_f32_fp8(v1.y, true);
        e += 8;
    }
    if (lenp & 4) {
        int i0 = sp[e + g4];
        uint2 v = *(const uint2*)(ybase + ((size_t)(unsigned)i0 << 7));
        a01 += __builtin_amdgcn_cvt_pk_f32_fp8(v.x, false);
        a23 += __builtin_amdgcn_cvt_pk_f32_fp8(v.x, true);
        a45 += __builtin_amdgcn_cvt_pk_f32_fp8(v.y, false);
        a67 += __builtin_amdgcn_cvt_pk_f32_fp8(v.y, true);
    }
    float a[8] = {a01[0], a01[1], a23[0], a23[1], a45[0], a45[1], a67[0], a67[1]};
    #pragma unroll
    for (int j = 0; j < 8; j++) {
        a[j] += __shfl_xor(a[j], 16, 64);
        a[j] += __shfl_xor(a[j], 32, 64);
    }
    float inv = 1.f / fmaxf((float)len, 1.f);

    float zf[8] = {bflo(zv.x), bfhi(zv.x), bflo(zv.y), bfhi(zv.y),
                   bflo(zv.z), bfhi(zv.z), bflo(zv.w), bfhi(zv.w)};
    float h[8];
    #pragma unroll
    for (int j = 0; j < 8; j++)
        h[j] = fmaxf(a[j] * inv + zf[j], 0.f);

    float p[3];
    #pragma unroll
    for (int qq = 0; qq < 3; qq++) {
        int q = g4 * 3 + qq;
        float s = 0.f;
        if (q < 11) {
            uint4 ww = *(const uint4*)&wsb[q * 128 + c16 * 8];
            s = h[0] * bflo(ww.x) + h[1] * bfhi(ww.x)
              + h[2] * bflo(ww.y) + h[3] * bfhi(ww.y)
              + h[4] * bflo(ww.z) + h[5] * bfhi(ww.z)
              + h[6] * bflo(ww.w) + h[7] * bfhi(ww.w);
        }
        #pragma unroll
        for (int d = 1; d < 16; d <<= 1)
            s += __shfl_xor(s, d, 64);
        p[qq] = s;
    }
    if (c16 == 0) {
        #pragma unroll
        for (int qq = 0; qq < 3; qq++) {
            int q = g4 * 3 + qq;
            if (q >= 11) continue;
            float val = p[qq] + w[(size_t)node * 16 + q] + cq[q];
            if (q == 0) {
                float al = palpha[0];
                float aa = 1.f / (1.f + expf(-al));
                outF[node] = aa * rrs[node] + (1.f - aa) * val;
            } else {
                outL[(size_t)node * NCRIT + q - 1] = val;
            }
        }
    }
}

extern "C" void kernel_launch(void* const* d_in, const int* in_sizes, int n_in,
                              void* d_out, int out_size, void* d_ws, size_t ws_size,
                              hipStream_t stream) {
    const float* x      = (const float*)d_in[0];
    const int*   ei     = (const int*)d_in[1];
    const float* rrs    = (const float*)d_in[2];
    const float* Wl     = (const float*)d_in[3];
    const float* bl     = (const float*)d_in[4];
    const float* Wr     = (const float*)d_in[5];
    const float* Wres   = (const float*)d_in[6];
    const float* bres   = (const float*)d_in[7];
    const float* wscore = (const float*)d_in[8];
    const float* bscore = (const float*)d_in[9];
    const float* wcrit  = (const float*)d_in[10];
    const float* bcrit  = (const float*)d_in[11];
    const float* alpha  = (const float*)d_in[12];

    int N = in_sizes[0] / DIN;
    int E = in_sizes[1] / 2;
    const int* srcv = ei;
    const int* dstv = ei + E;

    int nB = (N + 511) >> BSH;
    int capb = (int)alignup((size_t)(E / (nB > 0 ? nB : 1)) * 2 + 512 * 4 + 256, 16);

    char* p = (char*)d_ws;
    int* bcnt  = (int*)p; p += alignup((size_t)nB * 16 * 4, 256);
    int* bpool = (int*)p; p += alignup((size_t)nB * capb * 4, 256);
    int2* ocnt = (int2*)p; p += alignup((size_t)N * 8, 256);
    int* sidx  = (int*)p; p += alignup((size_t)nB * capb * 4, 256);
    bf16* WcatT = (bf16*)p; p += alignup((size_t)32 * 272 * 16, 256);
    unsigned char* yq = (unsigned char*)p; p += alignup((size_t)(N + 1) * HDIM, 256);
    bf16* z    = (bf16*)p; p += alignup((size_t)N * HDIM * 2, 256);
    float* w   = (float*)p; p += alignup((size_t)N * 16 * 4, 256);
    float* cq  = (float*)p; p += 256;

    hipMemsetAsync(bcnt, 0, (size_t)nB * 16 * 4, stream);

    k_bucket2<<<81 + (E + EPB - 1) / EPB, 256, 0, stream>>>(
        srcv, dstv, E, bcnt, bpool, capb, nB, Wl, Wr, Wres, wscore, wcrit,
        bres, bscore, bcrit, WcatT, cq);

    k_fingemm<<<nB + 256, 512, 0, stream>>>(bcnt, bpool, capb, nB, ocnt, sidx,
                                            x, WcatT, N, yq, z, w, bl);

    float* outF = (float*)d_out;
    float* outL = outF + N;
    k_gather<<<(N + 3) / 4, 256, 0, stream>>>(yq, z, w, cq, ocnt, sidx,
                                              wscore, wcrit, rrs, alpha, N, outF, outL);
}